// Round 1
// baseline (185.656 us; speedup 1.0000x reference)
//
#include <hip/hip_runtime.h>

// ChannelAttention fused kernel for MI355X (gfx950).
// B=4, L=16384, C=128, H=8, hd=16. Tokens M = 65536.
//
// Pipeline per 64-token block (256 threads, 4 waves):
//   stage 0: x tile (64x128 f32) -> LDS as bf16 (stride 136 for alignment/banks)
//   stage A: qkv = x @ Wqkv + b  via mfma_f32_16x16x32_bf16, acc fp32 in regs
//            (wave owns 16 token rows x all 384 cols -> acc[24] f32x4)
//   stage B: per-token 16x16 channel softmax-attention, fully fp32 in registers,
//            cross-channel via __shfl within each 16-lane quad
//   stage C: out = o @ Wproj + b via MFMA (o round-tripped through LDS as bf16
//            to convert C/D layout -> A layout), fp32 store.
// Weights are pre-transposed+bf16-converted into d_ws ([N][K] so B-fragments
// are 8 contiguous bf16 = one 16B load per lane).

typedef __attribute__((ext_vector_type(8))) short bf16x8;
typedef __attribute__((ext_vector_type(4))) float f32x4;

#define TILE_M 64
#define XS_STRIDE 136  // 136*2B = 272B row stride: 16B-aligned, 2-way bank alias (free)

__device__ __forceinline__ unsigned short f2bf(float f) {
    unsigned int u = __builtin_bit_cast(unsigned int, f);
    u += 0x7fffu + ((u >> 16) & 1u);   // round-to-nearest-even
    return (unsigned short)(u >> 16);
}

__global__ void prep_weights(const float* __restrict__ wqkv,
                             const float* __restrict__ wproj,
                             unsigned short* __restrict__ wqkvT,
                             unsigned short* __restrict__ wprojT) {
    int idx = blockIdx.x * 256 + threadIdx.x;
    if (idx < 384 * 128) {               // wqkvT[n][k] = bf16(wqkv[k][n])
        int n = idx >> 7, k = idx & 127;
        wqkvT[idx] = f2bf(wqkv[k * 384 + n]);
    }
    if (idx < 128 * 128) {               // wprojT[n][k] = bf16(wproj[k][n])
        int n = idx >> 7, k = idx & 127;
        wprojT[idx] = f2bf(wproj[k * 128 + n]);
    }
}

__global__ __launch_bounds__(256) void fused_channel_attn(
    const float* __restrict__ x,
    const unsigned short* __restrict__ wqkvT,
    const float* __restrict__ bqkv,
    const unsigned short* __restrict__ wprojT,
    const float* __restrict__ bproj,
    float* __restrict__ out)
{
    __shared__ __align__(16) unsigned short xs[TILE_M * XS_STRIDE];

    const int tid = threadIdx.x;
    const long base_tok = (long)blockIdx.x * TILE_M;

    // ---- stage 0: load x tile (64 x 128 f32), convert to bf16 in LDS
    const float4* xv = (const float4*)(x + base_tok * 128);
#pragma unroll
    for (int i = 0; i < 8; ++i) {
        int v = i * 256 + tid;          // 0..2047 float4s in tile
        int t = v >> 5;                 // 32 float4 per token row
        int c4 = v & 31;
        float4 f = xv[t * 32 + c4];
        int o = t * XS_STRIDE + c4 * 4;
        xs[o]     = f2bf(f.x);
        xs[o + 1] = f2bf(f.y);
        xs[o + 2] = f2bf(f.z);
        xs[o + 3] = f2bf(f.w);
    }
    __syncthreads();

    const int lane = tid & 63;
    const int wave = tid >> 6;
    const int col  = lane & 15;   // MFMA C/D col, A row (m), B col (n)
    const int quad = lane >> 4;   // k-chunk selector / C/D row group

    // ---- stage A: qkv[64][384] = x @ Wqkv   (wave: 16 tokens x 24 n-tiles)
    f32x4 acc[24];
#pragma unroll
    for (int n = 0; n < 24; ++n) acc[n] = (f32x4){0.f, 0.f, 0.f, 0.f};

#pragma unroll
    for (int ks = 0; ks < 4; ++ks) {
        // A frag: A[m=col][k = ks*32 + quad*8 + j], token = wave*16+col
        bf16x8 afrag = *(const bf16x8*)&xs[(wave * 16 + col) * XS_STRIDE + ks * 32 + quad * 8];
#pragma unroll
        for (int n = 0; n < 24; ++n) {
            // B frag: B[k][n-col]: wqkvT[n*16+col][k], 8 contiguous k
            bf16x8 bfrag = *(const bf16x8*)&wqkvT[(n * 16 + col) * 128 + ks * 32 + quad * 8];
            acc[n] = __builtin_amdgcn_mfma_f32_16x16x32_bf16(afrag, bfrag, acc[n], 0, 0, 0);
        }
    }
    // + b_qkv (bias depends only on channel = n*16+col)
#pragma unroll
    for (int n = 0; n < 24; ++n) {
        float b = bqkv[n * 16 + col];
        acc[n][0] += b; acc[n][1] += b; acc[n][2] += b; acc[n][3] += b;
    }

    // ---- stage B: per-token channel attention, fp32 in registers.
    // acc layout: acc[n][r] = qkv[token = wave*16 + quad*4 + r][ch = n*16 + col]
    // head h: q = acc[h], k = acc[h+8], v = acc[h+16]; lane's col is the channel idx.
    const float sl2e = 0.08838834764831845f * 1.44269504088896340f; // scale * log2(e)
    const int srcbase = lane & 48;  // keep shuffles within this 16-lane quad
    float oreg[8][4];
#pragma unroll
    for (int h = 0; h < 8; ++h) {
#pragma unroll
        for (int r = 0; r < 4; ++r) {
            float q  = acc[h][r] * sl2e;
            float kk = acc[h + 8][r];
            float vv = acc[h + 16][r];
            float den = 0.f, num = 0.f;
#pragma unroll
            for (int j = 0; j < 16; ++j) {
                float kj = __shfl(kk, srcbase | j, 64);
                float vj = __shfl(vv, srcbase | j, 64);
                float e = __builtin_amdgcn_exp2f(q * kj);
                den += e;
                num = fmaf(e, vj, num);
            }
            oreg[h][r] = num * __builtin_amdgcn_rcpf(den);
        }
    }

    // ---- layout round-trip: o (C/D layout) -> LDS bf16 (A layout for stage C)
    __syncthreads();   // all waves done reading xs
#pragma unroll
    for (int h = 0; h < 8; ++h)
#pragma unroll
        for (int r = 0; r < 4; ++r)
            xs[(wave * 16 + quad * 4 + r) * XS_STRIDE + h * 16 + col] = f2bf(oreg[h][r]);
    __syncthreads();

    // ---- stage C: out[64][128] = o @ Wproj + b
    f32x4 acc2[8];
#pragma unroll
    for (int n = 0; n < 8; ++n) acc2[n] = (f32x4){0.f, 0.f, 0.f, 0.f};
#pragma unroll
    for (int ks = 0; ks < 4; ++ks) {
        bf16x8 afrag = *(const bf16x8*)&xs[(wave * 16 + col) * XS_STRIDE + ks * 32 + quad * 8];
#pragma unroll
        for (int n = 0; n < 8; ++n) {
            bf16x8 bfrag = *(const bf16x8*)&wprojT[(n * 16 + col) * 128 + ks * 32 + quad * 8];
            acc2[n] = __builtin_amdgcn_mfma_f32_16x16x32_bf16(afrag, bfrag, acc2[n], 0, 0, 0);
        }
    }
    // epilogue: + b_proj, store fp32 (lanes 0..15 -> 64B contiguous per row)
#pragma unroll
    for (int n = 0; n < 8; ++n) {
        float b = bproj[n * 16 + col];
#pragma unroll
        for (int r = 0; r < 4; ++r) {
            long t = base_tok + wave * 16 + quad * 4 + r;
            out[t * 128 + n * 16 + col] = acc2[n][r] + b;
        }
    }
}

extern "C" void kernel_launch(void* const* d_in, const int* in_sizes, int n_in,
                              void* d_out, int out_size, void* d_ws, size_t ws_size,
                              hipStream_t stream) {
    const float* x     = (const float*)d_in[0];
    const float* wqkv  = (const float*)d_in[1];
    const float* bqkv  = (const float*)d_in[2];
    const float* wproj = (const float*)d_in[3];
    const float* bproj = (const float*)d_in[4];
    float* out = (float*)d_out;

    unsigned short* wqkvT  = (unsigned short*)d_ws;           // 384*128 bf16
    unsigned short* wprojT = wqkvT + 384 * 128;               // 128*128 bf16

    prep_weights<<<192, 256, 0, stream>>>(wqkv, wproj, wqkvT, wprojT);

    const int tokens = in_sizes[0] / 128;                     // 65536
    fused_channel_attn<<<tokens / TILE_M, 256, 0, stream>>>(
        x, wqkvT, bqkv, wprojT, bproj, out);
}

// Round 2
// 171.145 us; speedup vs baseline: 1.0848x; 1.0848x over previous
//
#include <hip/hip_runtime.h>

// ChannelAttention fused kernel for MI355X (gfx950), round 1.
// B=4, L=16384, C=128, H=8, hd=16. Tokens M = 65536.
//
// Per 64-token block (256 threads, 4 waves; wave owns 16 tokens):
//   stage A: afrags straight from global x (f32->bf16 in regs);
//            qkv = x @ Wqkv + b via mfma_f32_16x16x32_bf16 (fp32 acc, 96 MFMA/wave)
//   transpose: qkv -> LDS bf16 [64][392] (stride 392: 16B-aligned rows AND
//            uniform 8 words/bank for the stage-B b128 reads)
//   stage B: lane owns 2 (token,head) pairs; q,k,v (16 floats each) read as
//            2x ds_read_b128 per vector; attention fully in-register fp32:
//            256 exp2 + fma per pair. NO cross-lane ops.
//   stage C: o -> LDS bf16 A-layout (stride 136, overlaps qkv region after
//            barrier), out = o @ Wproj + b via MFMA, fp32 store.
// Weights pre-transposed+bf16 in d_ws: [N][K] so B-frags are 16B loads (L2-hot).

typedef __attribute__((ext_vector_type(8))) short bf16x8;
typedef __attribute__((ext_vector_type(4))) float f32x4;

#define TILE_M 64
#define QKV_STRIDE 392   // bf16 elems per token row (>=384); 392*2=784 B, 16B aligned
#define O_STRIDE 136     // bf16 elems per o row

__device__ __forceinline__ unsigned short f2bf(float f) {
    unsigned int u = __builtin_bit_cast(unsigned int, f);
    u += 0x7fffu + ((u >> 16) & 1u);   // round-to-nearest-even
    return (unsigned short)(u >> 16);
}
__device__ __forceinline__ float bf2f(unsigned short h) {
    unsigned int u = ((unsigned int)h) << 16;
    return __builtin_bit_cast(float, u);
}

__global__ void prep_weights(const float* __restrict__ wqkv,
                             const float* __restrict__ wproj,
                             unsigned short* __restrict__ wqkvT,
                             unsigned short* __restrict__ wprojT) {
    int idx = blockIdx.x * 256 + threadIdx.x;
    if (idx < 384 * 128) {               // wqkvT[n][k] = bf16(wqkv[k][n])
        int n = idx >> 7, k = idx & 127;
        wqkvT[idx] = f2bf(wqkv[k * 384 + n]);
    }
    if (idx < 128 * 128) {               // wprojT[n][k] = bf16(wproj[k][n])
        int n = idx >> 7, k = idx & 127;
        wprojT[idx] = f2bf(wproj[k * 128 + n]);
    }
}

__global__ __launch_bounds__(256) void fused_channel_attn(
    const float* __restrict__ x,
    const unsigned short* __restrict__ wqkvT,
    const float* __restrict__ bqkv,
    const unsigned short* __restrict__ wprojT,
    const float* __restrict__ bproj,
    float* __restrict__ out)
{
    __shared__ __align__(16) unsigned short us[TILE_M * QKV_STRIDE];  // 50176 B

    const int tid  = threadIdx.x;
    const int lane = tid & 63;
    const int wave = tid >> 6;
    const int col  = lane & 15;   // MFMA C/D col == A row (m) == B col (n)
    const int quad = lane >> 4;
    const long base_tok = (long)blockIdx.x * TILE_M;

    // ---- stage A: afrags direct from global (row = this lane's token)
    const float* xrow = x + (base_tok + wave * 16 + col) * 128;
    bf16x8 afr[4];
#pragma unroll
    for (int ks = 0; ks < 4; ++ks) {
        const float4* p = (const float4*)(xrow + ks * 32 + quad * 8);
        float4 f0 = p[0], f1 = p[1];
        bf16x8 a;
        a[0] = f2bf(f0.x); a[1] = f2bf(f0.y); a[2] = f2bf(f0.z); a[3] = f2bf(f0.w);
        a[4] = f2bf(f1.x); a[5] = f2bf(f1.y); a[6] = f2bf(f1.z); a[7] = f2bf(f1.w);
        afr[ks] = a;
    }

    // qkv[16 tok][384 ch] per wave: acc[n][r] = qkv[wave*16+quad*4+r][n*16+col]
    f32x4 acc[24];
#pragma unroll
    for (int n = 0; n < 24; ++n) acc[n] = (f32x4){0.f, 0.f, 0.f, 0.f};
#pragma unroll
    for (int ks = 0; ks < 4; ++ks) {
#pragma unroll
        for (int n = 0; n < 24; ++n) {
            bf16x8 bfrag = *(const bf16x8*)&wqkvT[(n * 16 + col) * 128 + ks * 32 + quad * 8];
            acc[n] = __builtin_amdgcn_mfma_f32_16x16x32_bf16(afr[ks], bfrag, acc[n], 0, 0, 0);
        }
    }
#pragma unroll
    for (int n = 0; n < 24; ++n) {
        float b = bqkv[n * 16 + col];
        acc[n][0] += b; acc[n][1] += b; acc[n][2] += b; acc[n][3] += b;
    }

    // ---- transpose: qkv -> LDS bf16 [tok][ch], scattered b16 writes
#pragma unroll
    for (int n = 0; n < 24; ++n)
#pragma unroll
        for (int r = 0; r < 4; ++r)
            us[(wave * 16 + quad * 4 + r) * QKV_STRIDE + n * 16 + col] = f2bf(acc[n][r]);
    __syncthreads();

    // ---- stage B: lane owns (t = lane&15, h = lane>>4 [+4]) pairs
    const int t  = lane & 15;
    const int h0 = lane >> 4;
    const unsigned short* qrow = &us[(wave * 16 + t) * QKV_STRIDE];

    bf16x8 qr[2], qr2[2], kr[2], kr2[2], vr[2], vr2[2];
#pragma unroll
    for (int p = 0; p < 2; ++p) {
        int h = h0 + 4 * p;
        qr [p] = *(const bf16x8*)(qrow + h * 16);
        qr2[p] = *(const bf16x8*)(qrow + h * 16 + 8);
        kr [p] = *(const bf16x8*)(qrow + 128 + h * 16);
        kr2[p] = *(const bf16x8*)(qrow + 128 + h * 16 + 8);
        vr [p] = *(const bf16x8*)(qrow + 256 + h * 16);
        vr2[p] = *(const bf16x8*)(qrow + 256 + h * 16 + 8);
    }
    __syncthreads();   // all qkv reads done before o writes (regions overlap)

    const float sl2e = 0.08838834764831845f * 1.44269504088896340f; // scale*log2(e)
#pragma unroll
    for (int p = 0; p < 2; ++p) {
        int h = h0 + 4 * p;
        float kf[16], vf[16];
#pragma unroll
        for (int j = 0; j < 8; ++j) {
            kf[j]     = bf2f((unsigned short)kr [p][j]);
            kf[j + 8] = bf2f((unsigned short)kr2[p][j]);
            vf[j]     = bf2f((unsigned short)vr [p][j]);
            vf[j + 8] = bf2f((unsigned short)vr2[p][j]);
        }
        bf16x8 o0, o1;
#pragma unroll
        for (int i = 0; i < 16; ++i) {
            float qs = bf2f((unsigned short)(i < 8 ? qr[p][i & 7] : qr2[p][i & 7])) * sl2e;
            float den = 0.f, num = 0.f;
#pragma unroll
            for (int j = 0; j < 16; ++j) {
                float e = __builtin_amdgcn_exp2f(qs * kf[j]);
                den += e;
                num = fmaf(e, vf[j], num);
            }
            unsigned short ob = f2bf(num * __builtin_amdgcn_rcpf(den));
            if (i < 8) o0[i] = (short)ob; else o1[i & 7] = (short)ob;
        }
        // o[t][h*16..+15] -> LDS A-layout (stride 136), 2x b128 per pair
        *(bf16x8*)&us[(wave * 16 + t) * O_STRIDE + h * 16]     = o0;
        *(bf16x8*)&us[(wave * 16 + t) * O_STRIDE + h * 16 + 8] = o1;
    }
    __syncthreads();

    // ---- stage C: out = o @ Wproj + b
    f32x4 acc2[8];
#pragma unroll
    for (int n = 0; n < 8; ++n) acc2[n] = (f32x4){0.f, 0.f, 0.f, 0.f};
#pragma unroll
    for (int ks = 0; ks < 4; ++ks) {
        bf16x8 af = *(const bf16x8*)&us[(wave * 16 + col) * O_STRIDE + ks * 32 + quad * 8];
#pragma unroll
        for (int n = 0; n < 8; ++n) {
            bf16x8 bfrag = *(const bf16x8*)&wprojT[(n * 16 + col) * 128 + ks * 32 + quad * 8];
            acc2[n] = __builtin_amdgcn_mfma_f32_16x16x32_bf16(af, bfrag, acc2[n], 0, 0, 0);
        }
    }
#pragma unroll
    for (int n = 0; n < 8; ++n) {
        float b = bproj[n * 16 + col];
#pragma unroll
        for (int r = 0; r < 4; ++r) {
            long tt = base_tok + wave * 16 + quad * 4 + r;
            out[tt * 128 + n * 16 + col] = acc2[n][r] + b;
        }
    }
}

extern "C" void kernel_launch(void* const* d_in, const int* in_sizes, int n_in,
                              void* d_out, int out_size, void* d_ws, size_t ws_size,
                              hipStream_t stream) {
    const float* x     = (const float*)d_in[0];
    const float* wqkv  = (const float*)d_in[1];
    const float* bqkv  = (const float*)d_in[2];
    const float* wproj = (const float*)d_in[3];
    const float* bproj = (const float*)d_in[4];
    float* out = (float*)d_out;

    unsigned short* wqkvT  = (unsigned short*)d_ws;    // 384*128 bf16
    unsigned short* wprojT = wqkvT + 384 * 128;        // 128*128 bf16

    prep_weights<<<192, 256, 0, stream>>>(wqkv, wproj, wqkvT, wprojT);

    const int tokens = in_sizes[0] / 128;              // 65536
    fused_channel_attn<<<tokens / TILE_M, 256, 0, stream>>>(
        x, wqkvT, bqkv, wprojT, bproj, out);
}

// Round 3
// 157.325 us; speedup vs baseline: 1.1801x; 1.0878x over previous
//
#include <hip/hip_runtime.h>

// ChannelAttention fused kernel for MI355X (gfx950), round 2.
// B=4, L=16384, C=128, H=8, hd=16. Tokens M = 65536.
//
// R2 change vs R1: TILE_M 64->32 (same 256 threads) to double resident
// concurrency and halve the per-block latency chain. Per thread: 12 qkv acc
// tiles (48 VGPR), ONE (token,head) attention pair, 4 proj tiles. Bias folded
// into MFMA accumulator init. Target 5 waves/SIMD via __launch_bounds__(256,5).
//
// Per 32-token block (4 waves):
//   stage A: wave w -> m-tile (w&1), n-tiles [(w>>1)*12 .. +12);
//            afrags straight from global x (f32->bf16 in regs);
//            qkv = x @ Wqkv + b via mfma_f32_16x16x32_bf16 (fp32 acc)
//   transpose: qkv -> LDS bf16 [32][392] (stride 392: 16B-aligned rows, and
//            392/2=196 words = 4 mod 32 -> b128 accesses hit the free 2-way min)
//   stage B: thread owns (t = tid&31, h = tid>>5); q,k,v via 6x ds_read_b128;
//            attention fully in-register fp32: 256 exp2 + fma. No cross-lane.
//   stage C: o -> LDS bf16 A-layout (stride 136, overlaps qkv region after
//            barrier), out = o @ Wproj + b via MFMA, fp32 store.
// Weights pre-transposed+bf16 in d_ws: [N][K] so B-frags are 16B loads (L1/L2-hot).

typedef __attribute__((ext_vector_type(8))) short bf16x8;
typedef __attribute__((ext_vector_type(4))) float f32x4;

#define TILE_M 32
#define QKV_STRIDE 392   // bf16 elems per token row (>=384)
#define O_STRIDE 136     // bf16 elems per o row

__device__ __forceinline__ unsigned short f2bf(float f) {
    unsigned int u = __builtin_bit_cast(unsigned int, f);
    u += 0x7fffu + ((u >> 16) & 1u);   // round-to-nearest-even
    return (unsigned short)(u >> 16);
}
__device__ __forceinline__ float bf2f(unsigned short h) {
    unsigned int u = ((unsigned int)h) << 16;
    return __builtin_bit_cast(float, u);
}

__global__ void prep_weights(const float* __restrict__ wqkv,
                             const float* __restrict__ wproj,
                             unsigned short* __restrict__ wqkvT,
                             unsigned short* __restrict__ wprojT) {
    int idx = blockIdx.x * 256 + threadIdx.x;
    if (idx < 384 * 128) {               // wqkvT[n][k] = bf16(wqkv[k][n])
        int n = idx >> 7, k = idx & 127;
        wqkvT[idx] = f2bf(wqkv[k * 384 + n]);
    }
    if (idx < 128 * 128) {               // wprojT[n][k] = bf16(wproj[k][n])
        int n = idx >> 7, k = idx & 127;
        wprojT[idx] = f2bf(wproj[k * 128 + n]);
    }
}

__global__ __launch_bounds__(256, 5) void fused_channel_attn(
    const float* __restrict__ x,
    const unsigned short* __restrict__ wqkvT,
    const float* __restrict__ bqkv,
    const unsigned short* __restrict__ wprojT,
    const float* __restrict__ bproj,
    float* __restrict__ out)
{
    __shared__ __align__(16) unsigned short us[TILE_M * QKV_STRIDE];  // 25088 B

    const int tid  = threadIdx.x;
    const int lane = tid & 63;
    const int wave = tid >> 6;
    const int col  = lane & 15;   // MFMA C/D col == A row (m) == B col (n)
    const int quad = lane >> 4;
    const long base_tok = (long)blockIdx.x * TILE_M;

    const int m  = wave & 1;        // m-tile (16 tokens) this wave computes
    const int nb = (wave >> 1) * 12; // first of 12 n-tiles this wave computes

    // ---- stage A: afrags direct from global (row = this lane's token)
    const float* xrow = x + (base_tok + m * 16 + col) * 128;
    bf16x8 afr[4];
#pragma unroll
    for (int ks = 0; ks < 4; ++ks) {
        const float4* p = (const float4*)(xrow + ks * 32 + quad * 8);
        float4 f0 = p[0], f1 = p[1];
        bf16x8 a;
        a[0] = f2bf(f0.x); a[1] = f2bf(f0.y); a[2] = f2bf(f0.z); a[3] = f2bf(f0.w);
        a[4] = f2bf(f1.x); a[5] = f2bf(f1.y); a[6] = f2bf(f1.z); a[7] = f2bf(f1.w);
        afr[ks] = a;
    }

    // acc[j][r] = qkv[m*16 + quad*4 + r][(nb+j)*16 + col]; init = bias splat
    f32x4 acc[12];
#pragma unroll
    for (int j = 0; j < 12; ++j) {
        float b = bqkv[(nb + j) * 16 + col];
        acc[j] = (f32x4){b, b, b, b};
    }
#pragma unroll
    for (int ks = 0; ks < 4; ++ks) {
#pragma unroll
        for (int j = 0; j < 12; ++j) {
            bf16x8 bfrag = *(const bf16x8*)&wqkvT[((nb + j) * 16 + col) * 128 + ks * 32 + quad * 8];
            acc[j] = __builtin_amdgcn_mfma_f32_16x16x32_bf16(afr[ks], bfrag, acc[j], 0, 0, 0);
        }
    }

    // ---- transpose: qkv -> LDS bf16 [tok][ch]
#pragma unroll
    for (int j = 0; j < 12; ++j)
#pragma unroll
        for (int r = 0; r < 4; ++r)
            us[(m * 16 + quad * 4 + r) * QKV_STRIDE + (nb + j) * 16 + col] = f2bf(acc[j][r]);
    __syncthreads();

    // ---- stage B: thread owns (t = tid&31, h = tid>>5)
    const int t = tid & 31;
    const int h = tid >> 5;
    const unsigned short* qrow = &us[t * QKV_STRIDE + h * 16];

    bf16x8 qr  = *(const bf16x8*)(qrow);
    bf16x8 qr2 = *(const bf16x8*)(qrow + 8);
    bf16x8 kr  = *(const bf16x8*)(qrow + 128);
    bf16x8 kr2 = *(const bf16x8*)(qrow + 136);
    bf16x8 vr  = *(const bf16x8*)(qrow + 256);
    bf16x8 vr2 = *(const bf16x8*)(qrow + 264);
    __syncthreads();   // all qkv reads done before o writes (regions overlap)

    const float sl2e = 0.08838834764831845f * 1.44269504088896340f; // scale*log2(e)
    float kf[16], vf[16];
#pragma unroll
    for (int j = 0; j < 8; ++j) {
        kf[j]     = bf2f((unsigned short)kr[j]);
        kf[j + 8] = bf2f((unsigned short)kr2[j]);
        vf[j]     = bf2f((unsigned short)vr[j]);
        vf[j + 8] = bf2f((unsigned short)vr2[j]);
    }
    bf16x8 o0, o1;
#pragma unroll
    for (int i = 0; i < 16; ++i) {
        float qs = bf2f((unsigned short)(i < 8 ? qr[i & 7] : qr2[i & 7])) * sl2e;
        float den = 0.f, num = 0.f;
#pragma unroll
        for (int j = 0; j < 16; ++j) {
            float e = __builtin_amdgcn_exp2f(qs * kf[j]);
            den += e;
            num = fmaf(e, vf[j], num);
        }
        unsigned short ob = f2bf(num * __builtin_amdgcn_rcpf(den));
        if (i < 8) o0[i] = (short)ob; else o1[i & 7] = (short)ob;
    }
    // o[t][h*16..+15] -> LDS A-layout (stride 136), 2x b128
    *(bf16x8*)&us[t * O_STRIDE + h * 16]     = o0;
    *(bf16x8*)&us[t * O_STRIDE + h * 16 + 8] = o1;
    __syncthreads();

    // ---- stage C: out = o @ Wproj + b. Wave: m-tile (w&1), n-tiles [(w>>1)*4..+4)
    const int nb2 = (wave >> 1) * 4;
    bf16x8 af[4];
#pragma unroll
    for (int ks = 0; ks < 4; ++ks)
        af[ks] = *(const bf16x8*)&us[(m * 16 + col) * O_STRIDE + ks * 32 + quad * 8];

    f32x4 acc2[4];
#pragma unroll
    for (int n = 0; n < 4; ++n) {
        float b = bproj[(nb2 + n) * 16 + col];
        acc2[n] = (f32x4){b, b, b, b};
    }
#pragma unroll
    for (int ks = 0; ks < 4; ++ks) {
#pragma unroll
        for (int n = 0; n < 4; ++n) {
            bf16x8 bfrag = *(const bf16x8*)&wprojT[((nb2 + n) * 16 + col) * 128 + ks * 32 + quad * 8];
            acc2[n] = __builtin_amdgcn_mfma_f32_16x16x32_bf16(af[ks], bfrag, acc2[n], 0, 0, 0);
        }
    }
#pragma unroll
    for (int n = 0; n < 4; ++n)
#pragma unroll
        for (int r = 0; r < 4; ++r) {
            long tt = base_tok + m * 16 + quad * 4 + r;
            out[tt * 128 + (nb2 + n) * 16 + col] = acc2[n][r];
        }
}

extern "C" void kernel_launch(void* const* d_in, const int* in_sizes, int n_in,
                              void* d_out, int out_size, void* d_ws, size_t ws_size,
                              hipStream_t stream) {
    const float* x     = (const float*)d_in[0];
    const float* wqkv  = (const float*)d_in[1];
    const float* bqkv  = (const float*)d_in[2];
    const float* wproj = (const float*)d_in[3];
    const float* bproj = (const float*)d_in[4];
    float* out = (float*)d_out;

    unsigned short* wqkvT  = (unsigned short*)d_ws;    // 384*128 bf16
    unsigned short* wprojT = wqkvT + 384 * 128;        // 128*128 bf16

    prep_weights<<<192, 256, 0, stream>>>(wqkv, wproj, wqkvT, wprojT);

    const int tokens = in_sizes[0] / 128;              // 65536
    fused_channel_attn<<<tokens / TILE_M, 256, 0, stream>>>(
        x, wqkvT, bqkv, wprojT, bproj, out);
}

// Round 4
// 136.776 us; speedup vs baseline: 1.3574x; 1.1502x over previous
//
#include <hip/hip_runtime.h>

// ChannelAttention fused kernel for MI355X (gfx950), round 3.
// B=4, L=16384, C=128, H=8, hd=16. Tokens M = 65536.
//
// R3 change vs R2: attack VMEM-latency serialization (R2: VGPR=48 ->
// weight-fragment loads issued one-at-a-time). Now:
//   - __launch_bounds__(256,4): 128-VGPR budget.
//   - stage A: wave owns 6 n-tiles x BOTH m-tiles; per ks the 6 bfrags are
//     loaded as a batch (6 loads in flight), each feeds 2 MFMAs; unrolled ks
//     loop lets the scheduler overlap next batch's loads with current MFMAs.
//   - stage C: 2 n-tiles x 2 m-tiles per wave, same batching.
//
// Per 32-token block (4 waves):
//   stage A: qkv = x @ Wqkv + b (bias folded into acc init), fp32 acc
//   transpose: qkv -> LDS bf16 [32][392]
//   stage B: thread owns (t = tid&31, h = tid>>5); attention in-register fp32,
//            256 exp2/thread, no cross-lane ops
//   stage C: o -> LDS bf16 (stride 136, overlapped region), out = o@Wproj + b
// Weights pre-transposed+bf16 in d_ws: [N][K] so B-frags are 16B loads.

typedef __attribute__((ext_vector_type(8))) short bf16x8;
typedef __attribute__((ext_vector_type(4))) float f32x4;

#define TILE_M 32
#define QKV_STRIDE 392   // bf16 elems per token row (>=384)
#define O_STRIDE 136     // bf16 elems per o row

__device__ __forceinline__ unsigned short f2bf(float f) {
    unsigned int u = __builtin_bit_cast(unsigned int, f);
    u += 0x7fffu + ((u >> 16) & 1u);   // round-to-nearest-even
    return (unsigned short)(u >> 16);
}
__device__ __forceinline__ float bf2f(unsigned short h) {
    unsigned int u = ((unsigned int)h) << 16;
    return __builtin_bit_cast(float, u);
}

__global__ void prep_weights(const float* __restrict__ wqkv,
                             const float* __restrict__ wproj,
                             unsigned short* __restrict__ wqkvT,
                             unsigned short* __restrict__ wprojT) {
    int idx = blockIdx.x * 256 + threadIdx.x;
    if (idx < 384 * 128) {               // wqkvT[n][k] = bf16(wqkv[k][n])
        int n = idx >> 7, k = idx & 127;
        wqkvT[idx] = f2bf(wqkv[k * 384 + n]);
    }
    if (idx < 128 * 128) {               // wprojT[n][k] = bf16(wproj[k][n])
        int n = idx >> 7, k = idx & 127;
        wprojT[idx] = f2bf(wproj[k * 128 + n]);
    }
}

__global__ __launch_bounds__(256, 4) void fused_channel_attn(
    const float* __restrict__ x,
    const unsigned short* __restrict__ wqkvT,
    const float* __restrict__ bqkv,
    const unsigned short* __restrict__ wprojT,
    const float* __restrict__ bproj,
    float* __restrict__ out)
{
    __shared__ __align__(16) unsigned short us[TILE_M * QKV_STRIDE];  // 25088 B

    const int tid  = threadIdx.x;
    const int lane = tid & 63;
    const int wave = tid >> 6;
    const int col  = lane & 15;   // MFMA C/D col == A row (m) == B col (n)
    const int quad = lane >> 4;
    const long base_tok = (long)blockIdx.x * TILE_M;

    const int nb = wave * 6;      // this wave's 6 qkv n-tiles (both m-tiles)

    // ---- stage A inputs: x fragments for both m-tiles, all ks — 16 HBM
    // loads issued up front (max MLP on the longest-latency loads).
    float4 xf[2][4][2];
#pragma unroll
    for (int m = 0; m < 2; ++m) {
        const float* xrow = x + (base_tok + m * 16 + col) * 128;
#pragma unroll
        for (int ks = 0; ks < 4; ++ks) {
            const float4* p = (const float4*)(xrow + ks * 32 + quad * 8);
            xf[m][ks][0] = p[0];
            xf[m][ks][1] = p[1];
        }
    }
    bf16x8 afr[2][4];
#pragma unroll
    for (int m = 0; m < 2; ++m)
#pragma unroll
        for (int ks = 0; ks < 4; ++ks) {
            float4 f0 = xf[m][ks][0], f1 = xf[m][ks][1];
            bf16x8 a;
            a[0] = f2bf(f0.x); a[1] = f2bf(f0.y); a[2] = f2bf(f0.z); a[3] = f2bf(f0.w);
            a[4] = f2bf(f1.x); a[5] = f2bf(f1.y); a[6] = f2bf(f1.z); a[7] = f2bf(f1.w);
            afr[m][ks] = a;
        }

    // acc[m][j][r] = qkv[m*16 + quad*4 + r][(nb+j)*16 + col]; init = bias
    f32x4 acc[2][6];
#pragma unroll
    for (int j = 0; j < 6; ++j) {
        float b = bqkv[(nb + j) * 16 + col];
        acc[0][j] = (f32x4){b, b, b, b};
        acc[1][j] = (f32x4){b, b, b, b};
    }
#pragma unroll
    for (int ks = 0; ks < 4; ++ks) {
        bf16x8 bfr[6];                 // batched: 6 loads in flight
#pragma unroll
        for (int j = 0; j < 6; ++j)
            bfr[j] = *(const bf16x8*)&wqkvT[((nb + j) * 16 + col) * 128 + ks * 32 + quad * 8];
#pragma unroll
        for (int j = 0; j < 6; ++j) {  // each bfrag feeds 2 MFMAs
            acc[0][j] = __builtin_amdgcn_mfma_f32_16x16x32_bf16(afr[0][ks], bfr[j], acc[0][j], 0, 0, 0);
            acc[1][j] = __builtin_amdgcn_mfma_f32_16x16x32_bf16(afr[1][ks], bfr[j], acc[1][j], 0, 0, 0);
        }
    }

    // ---- transpose: qkv -> LDS bf16 [tok][ch]
#pragma unroll
    for (int m = 0; m < 2; ++m)
#pragma unroll
        for (int j = 0; j < 6; ++j)
#pragma unroll
            for (int r = 0; r < 4; ++r)
                us[(m * 16 + quad * 4 + r) * QKV_STRIDE + (nb + j) * 16 + col] = f2bf(acc[m][j][r]);
    __syncthreads();

    // ---- stage B: thread owns (t = tid&31, h = tid>>5)
    const int t = tid & 31;
    const int h = tid >> 5;
    const unsigned short* qrow = &us[t * QKV_STRIDE + h * 16];

    bf16x8 qr  = *(const bf16x8*)(qrow);
    bf16x8 qr2 = *(const bf16x8*)(qrow + 8);
    bf16x8 kr  = *(const bf16x8*)(qrow + 128);
    bf16x8 kr2 = *(const bf16x8*)(qrow + 136);
    bf16x8 vr  = *(const bf16x8*)(qrow + 256);
    bf16x8 vr2 = *(const bf16x8*)(qrow + 264);
    __syncthreads();   // all qkv reads done before o writes (regions overlap)

    const float sl2e = 0.08838834764831845f * 1.44269504088896340f; // scale*log2(e)
    float kf[16], vf[16];
#pragma unroll
    for (int j = 0; j < 8; ++j) {
        kf[j]     = bf2f((unsigned short)kr[j]);
        kf[j + 8] = bf2f((unsigned short)kr2[j]);
        vf[j]     = bf2f((unsigned short)vr[j]);
        vf[j + 8] = bf2f((unsigned short)vr2[j]);
    }
    bf16x8 o0, o1;
#pragma unroll
    for (int i = 0; i < 16; ++i) {
        float qs = bf2f((unsigned short)(i < 8 ? qr[i & 7] : qr2[i & 7])) * sl2e;
        float den = 0.f, num = 0.f;
#pragma unroll
        for (int j = 0; j < 16; ++j) {
            float e = __builtin_amdgcn_exp2f(qs * kf[j]);
            den += e;
            num = fmaf(e, vf[j], num);
        }
        unsigned short ob = f2bf(num * __builtin_amdgcn_rcpf(den));
        if (i < 8) o0[i] = (short)ob; else o1[i & 7] = (short)ob;
    }
    // o[t][h*16..+15] -> LDS A-layout (stride 136), 2x b128
    *(bf16x8*)&us[t * O_STRIDE + h * 16]     = o0;
    *(bf16x8*)&us[t * O_STRIDE + h * 16 + 8] = o1;
    __syncthreads();

    // ---- stage C: out = o @ Wproj + b. Wave: 2 n-tiles x 2 m-tiles.
    const int nb2 = wave * 2;
    bf16x8 af2[2][4];
#pragma unroll
    for (int m = 0; m < 2; ++m)
#pragma unroll
        for (int ks = 0; ks < 4; ++ks)
            af2[m][ks] = *(const bf16x8*)&us[(m * 16 + col) * O_STRIDE + ks * 32 + quad * 8];

    f32x4 acc2[2][2];
#pragma unroll
    for (int n = 0; n < 2; ++n) {
        float b = bproj[(nb2 + n) * 16 + col];
        acc2[0][n] = (f32x4){b, b, b, b};
        acc2[1][n] = (f32x4){b, b, b, b};
    }
#pragma unroll
    for (int ks = 0; ks < 4; ++ks) {
        bf16x8 bb[2];
#pragma unroll
        for (int n = 0; n < 2; ++n)
            bb[n] = *(const bf16x8*)&wprojT[((nb2 + n) * 16 + col) * 128 + ks * 32 + quad * 8];
#pragma unroll
        for (int n = 0; n < 2; ++n) {
            acc2[0][n] = __builtin_amdgcn_mfma_f32_16x16x32_bf16(af2[0][ks], bb[n], acc2[0][n], 0, 0, 0);
            acc2[1][n] = __builtin_amdgcn_mfma_f32_16x16x32_bf16(af2[1][ks], bb[n], acc2[1][n], 0, 0, 0);
        }
    }
#pragma unroll
    for (int m = 0; m < 2; ++m)
#pragma unroll
        for (int n = 0; n < 2; ++n)
#pragma unroll
            for (int r = 0; r < 4; ++r) {
                long tt = base_tok + m * 16 + quad * 4 + r;
                out[tt * 128 + (nb2 + n) * 16 + col] = acc2[m][n][r];
            }
}

extern "C" void kernel_launch(void* const* d_in, const int* in_sizes, int n_in,
                              void* d_out, int out_size, void* d_ws, size_t ws_size,
                              hipStream_t stream) {
    const float* x     = (const float*)d_in[0];
    const float* wqkv  = (const float*)d_in[1];
    const float* bqkv  = (const float*)d_in[2];
    const float* wproj = (const float*)d_in[3];
    const float* bproj = (const float*)d_in[4];
    float* out = (float*)d_out;

    unsigned short* wqkvT  = (unsigned short*)d_ws;    // 384*128 bf16
    unsigned short* wprojT = wqkvT + 384 * 128;        // 128*128 bf16

    prep_weights<<<192, 256, 0, stream>>>(wqkv, wproj, wqkvT, wprojT);

    const int tokens = in_sizes[0] / 128;              // 65536
    fused_channel_attn<<<tokens / TILE_M, 256, 0, stream>>>(
        x, wqkvT, bqkv, wprojT, bproj, out);
}

// Round 5
// 131.744 us; speedup vs baseline: 1.4092x; 1.0382x over previous
//
#include <hip/hip_runtime.h>

// ChannelAttention fused kernel for MI355X (gfx950), round 4.
// B=4, L=16384, C=128, H=8, hd=16. Tokens M = 65536.
//
// R4 changes vs R3 (VALU-conversion tax + register starvation):
//   - qkv transpose now stores FP32 to LDS (ds_write_b32, zero convert ops);
//     stage B reads q/k/v as float4s (no bf16 unpack). LDS 49.7 KB.
//   - bf16 packing (x->A-frags, o->A-frags) via v_perm_b32 + round-half-up:
//     3 VALU per 2 elements instead of ~11.
//   - __launch_bounds__(256,3): 168-reg unified budget so the 16 x loads and
//     6-wide weight batches actually stay in flight (R3 got squeezed to 64).
//
// Per 32-token block (4 waves):
//   stage A: wave owns 6 n-tiles x both m-tiles; batched weight loads,
//            each bfrag feeds 2 MFMAs; bias folded into acc init.
//   transpose: qkv -> LDS fp32 [32][388]
//   stage B: thread owns (t = tid&31, h = tid>>5); 12x ds_read_b128;
//            attention fully in-register fp32: 256 exp2 + fma; no cross-lane.
//   stage C: o -> LDS bf16 (stride 136, overlaps qkv region after barrier),
//            out = o @ Wproj + b via MFMA, fp32 store.
// Weights pre-transposed+bf16 in d_ws: [N][K] so B-frags are 16B loads.

typedef __attribute__((ext_vector_type(8))) short bf16x8;
typedef __attribute__((ext_vector_type(4))) float f32x4;
typedef __attribute__((ext_vector_type(4))) unsigned int u32x4;

#define TILE_M 32
#define QKV_STRIDE_F 388   // fp32 elems per token row (>=384; 388%8==4 -> 16B aligned rows, spread banks)
#define O_STRIDE 136       // bf16 elems per o row

__device__ __forceinline__ unsigned short f2bf(float f) {
    unsigned int u = __builtin_bit_cast(unsigned int, f);
    u += 0x8000u;                      // round half up (cheap, <=0.5 ulp + tie bias)
    return (unsigned short)(u >> 16);
}
// pack two floats -> packed bf16x2 (lo in low short) in 3 VALU ops
__device__ __forceinline__ unsigned int pkbf(float lo, float hi) {
    unsigned int a = __builtin_bit_cast(unsigned int, lo) + 0x8000u;
    unsigned int b = __builtin_bit_cast(unsigned int, hi) + 0x8000u;
    return __builtin_amdgcn_perm(b, a, 0x07060302u);  // {hi16(b),hi16(a)}
}

__global__ void prep_weights(const float* __restrict__ wqkv,
                             const float* __restrict__ wproj,
                             unsigned short* __restrict__ wqkvT,
                             unsigned short* __restrict__ wprojT) {
    int idx = blockIdx.x * 256 + threadIdx.x;
    if (idx < 384 * 128) {               // wqkvT[n][k] = bf16(wqkv[k][n])
        int n = idx >> 7, k = idx & 127;
        wqkvT[idx] = f2bf(wqkv[k * 384 + n]);
    }
    if (idx < 128 * 128) {               // wprojT[n][k] = bf16(wproj[k][n])
        int n = idx >> 7, k = idx & 127;
        wprojT[idx] = f2bf(wproj[k * 128 + n]);
    }
}

__global__ __launch_bounds__(256, 3) void fused_channel_attn(
    const float* __restrict__ x,
    const unsigned short* __restrict__ wqkvT,
    const float* __restrict__ bqkv,
    const unsigned short* __restrict__ wprojT,
    const float* __restrict__ bproj,
    float* __restrict__ out)
{
    __shared__ __align__(16) float us_f[TILE_M * QKV_STRIDE_F];   // 49664 B
    unsigned short* us_o = (unsigned short*)us_f;                 // o region (reused after barrier)

    const int tid  = threadIdx.x;
    const int lane = tid & 63;
    const int wave = tid >> 6;
    const int col  = lane & 15;   // MFMA C/D col == A row (m) == B col (n)
    const int quad = lane >> 4;
    const long base_tok = (long)blockIdx.x * TILE_M;

    const int nb = wave * 6;      // this wave's 6 qkv n-tiles (both m-tiles)

    // ---- stage A: x fragments for both m-tiles, 16 loads in flight
    float4 xf[2][4][2];
#pragma unroll
    for (int m = 0; m < 2; ++m) {
        const float* xrow = x + (base_tok + m * 16 + col) * 128;
#pragma unroll
        for (int ks = 0; ks < 4; ++ks) {
            const float4* p = (const float4*)(xrow + ks * 32 + quad * 8);
            xf[m][ks][0] = p[0];
            xf[m][ks][1] = p[1];
        }
    }
    bf16x8 afr[2][4];
#pragma unroll
    for (int m = 0; m < 2; ++m)
#pragma unroll
        for (int ks = 0; ks < 4; ++ks) {
            float4 f0 = xf[m][ks][0], f1 = xf[m][ks][1];
            u32x4 a = {pkbf(f0.x, f0.y), pkbf(f0.z, f0.w),
                       pkbf(f1.x, f1.y), pkbf(f1.z, f1.w)};
            afr[m][ks] = __builtin_bit_cast(bf16x8, a);
        }

    // acc[m][j][r] = qkv[m*16 + quad*4 + r][(nb+j)*16 + col]; init = bias
    f32x4 acc[2][6];
#pragma unroll
    for (int j = 0; j < 6; ++j) {
        float b = bqkv[(nb + j) * 16 + col];
        acc[0][j] = (f32x4){b, b, b, b};
        acc[1][j] = (f32x4){b, b, b, b};
    }
#pragma unroll
    for (int ks = 0; ks < 4; ++ks) {
        bf16x8 bfr[6];                 // batched: 6 loads in flight
#pragma unroll
        for (int j = 0; j < 6; ++j)
            bfr[j] = *(const bf16x8*)&wqkvT[((nb + j) * 16 + col) * 128 + ks * 32 + quad * 8];
#pragma unroll
        for (int j = 0; j < 6; ++j) {  // each bfrag feeds 2 MFMAs
            acc[0][j] = __builtin_amdgcn_mfma_f32_16x16x32_bf16(afr[0][ks], bfr[j], acc[0][j], 0, 0, 0);
            acc[1][j] = __builtin_amdgcn_mfma_f32_16x16x32_bf16(afr[1][ks], bfr[j], acc[1][j], 0, 0, 0);
        }
    }

    // ---- transpose: qkv -> LDS fp32 [tok][ch] (plain b32 stores, no cvt)
#pragma unroll
    for (int m = 0; m < 2; ++m)
#pragma unroll
        for (int j = 0; j < 6; ++j)
#pragma unroll
            for (int r = 0; r < 4; ++r)
                us_f[(m * 16 + quad * 4 + r) * QKV_STRIDE_F + (nb + j) * 16 + col] = acc[m][j][r];
    __syncthreads();

    // ---- stage B: thread owns (t = tid&31, h = tid>>5)
    const int t = tid & 31;
    const int h = tid >> 5;
    const float* qkvrow = us_f + t * QKV_STRIDE_F + h * 16;

    float4 qv4[4], kv4[4], vv4[4];     // 12 ds_read_b128
#pragma unroll
    for (int c = 0; c < 4; ++c) {
        qv4[c] = ((const float4*)(qkvrow))[c];
        kv4[c] = ((const float4*)(qkvrow + 128))[c];
        vv4[c] = ((const float4*)(qkvrow + 256))[c];
    }
    __syncthreads();   // all qkv reads done before o writes (regions overlap)

    const float sl2e = 0.08838834764831845f * 1.44269504088896340f; // scale*log2(e)
    float qv[16], kf[16], vf[16];
#pragma unroll
    for (int c = 0; c < 4; ++c) {
        qv[4*c] = qv4[c].x; qv[4*c+1] = qv4[c].y; qv[4*c+2] = qv4[c].z; qv[4*c+3] = qv4[c].w;
        kf[4*c] = kv4[c].x; kf[4*c+1] = kv4[c].y; kf[4*c+2] = kv4[c].z; kf[4*c+3] = kv4[c].w;
        vf[4*c] = vv4[c].x; vf[4*c+1] = vv4[c].y; vf[4*c+2] = vv4[c].z; vf[4*c+3] = vv4[c].w;
    }
    float ov[16];
#pragma unroll
    for (int i = 0; i < 16; ++i) {
        float qs = qv[i] * sl2e;
        float den = 0.f, num = 0.f;
#pragma unroll
        for (int j = 0; j < 16; ++j) {
            float e = __builtin_amdgcn_exp2f(qs * kf[j]);
            den += e;
            num = fmaf(e, vf[j], num);
        }
        ov[i] = num * __builtin_amdgcn_rcpf(den);
    }
    // pack o -> bf16 (8 perms) and store 2x b128 to LDS A-layout (stride 136)
    u32x4 o0 = {pkbf(ov[0], ov[1]), pkbf(ov[2], ov[3]), pkbf(ov[4], ov[5]), pkbf(ov[6], ov[7])};
    u32x4 o1 = {pkbf(ov[8], ov[9]), pkbf(ov[10], ov[11]), pkbf(ov[12], ov[13]), pkbf(ov[14], ov[15])};
    *(u32x4*)&us_o[t * O_STRIDE + h * 16]     = o0;
    *(u32x4*)&us_o[t * O_STRIDE + h * 16 + 8] = o1;
    __syncthreads();

    // ---- stage C: out = o @ Wproj + b. Wave: 2 n-tiles x 2 m-tiles.
    const int nb2 = wave * 2;
    bf16x8 af2[2][4];
#pragma unroll
    for (int m = 0; m < 2; ++m)
#pragma unroll
        for (int ks = 0; ks < 4; ++ks)
            af2[m][ks] = *(const bf16x8*)&us_o[(m * 16 + col) * O_STRIDE + ks * 32 + quad * 8];

    f32x4 acc2[2][2];
#pragma unroll
    for (int n = 0; n < 2; ++n) {
        float b = bproj[(nb2 + n) * 16 + col];
        acc2[0][n] = (f32x4){b, b, b, b};
        acc2[1][n] = (f32x4){b, b, b, b};
    }
#pragma unroll
    for (int ks = 0; ks < 4; ++ks) {
        bf16x8 bb[2];
#pragma unroll
        for (int n = 0; n < 2; ++n)
            bb[n] = *(const bf16x8*)&wprojT[((nb2 + n) * 16 + col) * 128 + ks * 32 + quad * 8];
#pragma unroll
        for (int n = 0; n < 2; ++n) {
            acc2[0][n] = __builtin_amdgcn_mfma_f32_16x16x32_bf16(af2[0][ks], bb[n], acc2[0][n], 0, 0, 0);
            acc2[1][n] = __builtin_amdgcn_mfma_f32_16x16x32_bf16(af2[1][ks], bb[n], acc2[1][n], 0, 0, 0);
        }
    }
#pragma unroll
    for (int m = 0; m < 2; ++m)
#pragma unroll
        for (int n = 0; n < 2; ++n)
#pragma unroll
            for (int r = 0; r < 4; ++r) {
                long tt = base_tok + m * 16 + quad * 4 + r;
                out[tt * 128 + (nb2 + n) * 16 + col] = acc2[m][n][r];
            }
}

extern "C" void kernel_launch(void* const* d_in, const int* in_sizes, int n_in,
                              void* d_out, int out_size, void* d_ws, size_t ws_size,
                              hipStream_t stream) {
    const float* x     = (const float*)d_in[0];
    const float* wqkv  = (const float*)d_in[1];
    const float* bqkv  = (const float*)d_in[2];
    const float* wproj = (const float*)d_in[3];
    const float* bproj = (const float*)d_in[4];
    float* out = (float*)d_out;

    unsigned short* wqkvT  = (unsigned short*)d_ws;    // 384*128 bf16
    unsigned short* wprojT = wqkvT + 384 * 128;        // 128*128 bf16

    prep_weights<<<192, 256, 0, stream>>>(wqkv, wproj, wqkvT, wprojT);

    const int tokens = in_sizes[0] / 128;              // 65536
    fused_channel_attn<<<tokens / TILE_M, 256, 0, stream>>>(
        x, wqkvT, bqkv, wprojT, bproj, out);
}